// Round 5
// baseline (1856.816 us; speedup 1.0000x reference)
//
#include <hip/hip_runtime.h>
#include <hip/hip_bf16.h>
#include <stdint.h>

// ---------------------------------------------------------------------------
// GIN forward, round 5: aggregation with GUARANTEED XCD affinity — blocks
// read HW_REG_XCC_ID and pull 32-node chunks for their own XCD's column
// slice from per-slice atomic cursors (work-stealing fallback keeps it
// correct if the reg is degenerate). Radix-partition CSR, bf16 MFMA mm.
// ---------------------------------------------------------------------------

typedef __attribute__((ext_vector_type(8))) short short8;
typedef __attribute__((ext_vector_type(4))) float float4v;

#define BKT 512       // nodes per bucket (dst >> 9)
#define NBMAX 256     // max buckets held in LDS (NB = 196 here)
#define NS 8          // column slices (== XCD count)
#define SC 16         // columns per slice (NS*SC == 128)
// s_getreg imm: id=20 (HW_REG_XCC_ID), offset=0, size=32 -> (31<<11)|20
#define XCC_ID_IMM 63508

__device__ __forceinline__ float b2f_lo(unsigned int u) {
    return __uint_as_float(u << 16);
}
__device__ __forceinline__ float b2f_hi(unsigned int u) {
    return __uint_as_float(u & 0xffff0000u);
}
__device__ __forceinline__ unsigned short f2b(float f) {
    unsigned int u = __float_as_uint(f);
    return (unsigned short)((u + 0x7fffu + ((u >> 16) & 1u)) >> 16);  // RNE
}

// ---------------- edge-index dtype detection ----------------
__global__ void detect_i64_kernel(const unsigned int* ei, int* flag) {
    if (threadIdx.x == 0) {
        int is64 = 1;
        for (int e = 0; e < 64; ++e)
            if (ei[2 * e + 1] != 0u) { is64 = 0; break; }
        *flag = is64;
    }
}

__device__ __forceinline__ int edge_at(const int* ei32, int is64, long long pos) {
    if (is64) return (int)(((const long long*)ei32)[pos]);
    return ei32[pos];
}

// unpack edge_index into src/dst i32 arrays (coalesced)
__global__ void econv_kernel(const int* __restrict__ ei, const int* __restrict__ flag,
                             int* __restrict__ srcs, int* __restrict__ dsts, int E) {
    int e = blockIdx.x * blockDim.x + threadIdx.x;
    if (e >= E) return;
    int is64 = *flag;
    srcs[e] = edge_at(ei, is64, e);
    dsts[e] = edge_at(ei, is64, (long long)E + e);
}

// ---------------- radix partition pass 1: per-(block,bucket) histogram ----------------
__global__ __launch_bounds__(256) void part_hist_kernel(
        const int* __restrict__ dsts, int* __restrict__ bh, int E, int NB, int PB) {
    __shared__ int h[NBMAX];
    const int g = blockIdx.x, tid = threadIdx.x;
    for (int i = tid; i < NB; i += 256) h[i] = 0;
    __syncthreads();
    const int e0 = g * PB, e1 = min(e0 + PB, E);
    for (int e = e0 + tid; e < e1; e += 256)
        atomicAdd(&h[dsts[e] >> 9], 1);
    __syncthreads();
    for (int i = tid; i < NB; i += 256) bh[i * gridDim.x + g] = h[i];
}

// ---------------- generic multi-block exclusive scan ----------------
__global__ __launch_bounds__(1024) void scan1_kernel(
        const int* __restrict__ in, int* __restrict__ out,
        int* __restrict__ partial, int n) {
    __shared__ int sm[1024];
    const int t = threadIdx.x;
    const int i = blockIdx.x * 1024 + t;
    int v = (i < n) ? in[i] : 0;
    sm[t] = v;
    __syncthreads();
#pragma unroll
    for (int off = 1; off < 1024; off <<= 1) {
        int x = (t >= off) ? sm[t - off] : 0;
        __syncthreads();
        sm[t] += x;
        __syncthreads();
    }
    if (i < n) out[i] = sm[t] - v;
    if (t == 1023) partial[blockIdx.x] = sm[1023];
}

__global__ __launch_bounds__(128) void scan2_kernel(
        int* __restrict__ partial, int* __restrict__ blockoff, int g1) {
    __shared__ int sm[128];
    const int t = threadIdx.x;
    int v = (t < g1) ? partial[t] : 0;
    sm[t] = v;
    __syncthreads();
#pragma unroll
    for (int off = 1; off < 128; off <<= 1) {
        int x = (t >= off) ? sm[t - off] : 0;
        __syncthreads();
        sm[t] += x;
        __syncthreads();
    }
    blockoff[t] = sm[t] - v;
}

__global__ __launch_bounds__(1024) void scan3g_kernel(
        int* __restrict__ a, const int* __restrict__ blockoff, int n) {
    int i = blockIdx.x * 1024 + threadIdx.x;
    if (i < n) a[i] += blockoff[blockIdx.x];
}

// ---------------- pass 2: scatter edges into bucket-contiguous staging ----------------
// staged entry: (dlocal<<17) | src
__global__ __launch_bounds__(256) void part_scatter_kernel(
        const int* __restrict__ dsts, const int* __restrict__ srcs,
        const int* __restrict__ bhs, unsigned int* __restrict__ staged,
        int E, int NB, int PB) {
    __shared__ int cur[NBMAX];
    const int g = blockIdx.x, tid = threadIdx.x;
    for (int i = tid; i < NB; i += 256) cur[i] = bhs[i * gridDim.x + g];
    __syncthreads();
    const int e0 = g * PB, e1 = min(e0 + PB, E);
    for (int e = e0 + tid; e < e1; e += 256) {
        int d = dsts[e];
        int s = srcs[e];
        int b = d >> 9;
        int p = atomicAdd(&cur[b], 1);
        staged[p] = ((unsigned int)(d & (BKT - 1)) << 17) | (unsigned int)s;
    }
}

// ---------------- pass 3: per-bucket counting sort -> offs + csr ----------------
__global__ __launch_bounds__(256) void csr_local_kernel(
        const unsigned int* __restrict__ staged, const int* __restrict__ bhs,
        int* __restrict__ offs, int* __restrict__ csr, int N, int E, int NB, int G2) {
    __shared__ int hist[BKT];
    __shared__ int cur[BKT];
    const int b = blockIdx.x;
    const int tid = threadIdx.x;
    const int start = bhs[b * G2];
    const int end = (b + 1 < NB) ? bhs[(b + 1) * G2] : E;
    const int node0 = b * BKT;
    for (int i = tid; i < BKT; i += 256) hist[i] = 0;
    __syncthreads();
    for (int i = start + tid; i < end; i += 256)
        atomicAdd(&hist[staged[i] >> 17], 1);
    __syncthreads();
    const int i0 = tid * 2, i1 = i0 + 1;
    for (int off = 1; off < BKT; off <<= 1) {
        int v0 = (i0 >= off) ? hist[i0 - off] : 0;
        int v1 = (i1 >= off) ? hist[i1 - off] : 0;
        __syncthreads();
        hist[i0] += v0;
        hist[i1] += v1;
        __syncthreads();
    }
    for (int i = tid; i < BKT; i += 256) {
        int node = node0 + i;
        if (node < N) {
            int e0 = start + ((i == 0) ? 0 : hist[i - 1]);
            offs[node] = e0;
            cur[i] = e0;
        }
    }
    if (b == NB - 1 && tid == 0) offs[N] = E;
    __syncthreads();
    for (int i = start + tid; i < end; i += 256) {
        unsigned int v = staged[i];
        int dl = v >> 17;
        int src = (int)(v & 0x1ffff);
        int p = atomicAdd(&cur[dl], 1);
        csr[p] = src;
    }
}

// ---------------- conversions ----------------
__global__ void xconv_kernel(const float* __restrict__ x, unsigned short* __restrict__ xb,
                             int total_real, int total_pad) {
    int i = blockIdx.x * blockDim.x + threadIdx.x;
    if (i >= total_pad) return;
    xb[i] = (i < total_real) ? f2b(x[i]) : (unsigned short)0;
}

// Pack W[K x KOUT] (f32 row-major) into MFMA-B fragment order.
__global__ void packw_kernel(const float* __restrict__ W, unsigned short* __restrict__ out,
                             int K, int KOUT) {
    const int KS = K / 32;
    const int total = (KOUT / 16) * KS * 64;
    int id = blockIdx.x * blockDim.x + threadIdx.x;
    if (id >= total) return;
    const int l = id & 63;
    const int s = (id >> 6) % KS;
    const int t = id / (KS * 64);
    const int kbase = s * 32 + ((l >> 4) << 3);
    const int n = t * 16 + (l & 15);
#pragma unroll
    for (int j = 0; j < 8; ++j)
        out[(long long)id * 8 + j] = f2b(W[(long long)(kbase + j) * KOUT + n]);
}

// ---------------- XCD-affine aggregation ----------------
// H slice-major: Hs[s][node][SC]. Persistent blocks read their hardware XCD
// id and pull 32-node chunks for slice==xcd from per-slice cursors, so each
// XCD's gather set is exactly its own 3.2 MB slice (L2-resident). After a
// slice's cursor exhausts, blocks advance to the next slice (work stealing:
// correct even if XCC_ID is degenerate). 8 lanes/node, 2 cols/lane.
__global__ __launch_bounds__(256) void aggz_xcd_kernel(
        const unsigned short* __restrict__ Hs, const int* __restrict__ offs,
        const int* __restrict__ csr, const float* __restrict__ eps,
        unsigned short* __restrict__ Z, int* __restrict__ cursors,
        int n, int Mp) {
    __shared__ int s_sl, s_ch;
    const int tid = threadIdx.x;
    const int nchunks = (n + 31) >> 5;
    int xcd;
    if (tid == 0) {
        xcd = __builtin_amdgcn_s_getreg(XCC_ID_IMM) & (NS - 1);
        s_sl = xcd;
    }
    __syncthreads();
    int s = s_sl;
    int tries = 0;
    const float e = 1.0f + eps[0];
    while (tries < NS) {
        if (tid == 0) s_ch = atomicAdd(&cursors[s], 1);
        __syncthreads();
        const int chunk = s_ch;
        __syncthreads();
        if (chunk >= nchunks) { s = (s + 1) & (NS - 1); ++tries; continue; }
        const unsigned short* base = Hs + (long long)s * Mp * SC;
        const int node = chunk * 32 + (tid >> 3);
        const int c2 = (tid & 7) << 1;
        if (node < n) {
            const int beg = offs[node];
            const int end = offs[node + 1];
            float s0 = 0.f, s1 = 0.f;
            int i = beg;
            for (; i + 7 < end; i += 8) {
                int j0 = csr[i],     j1 = csr[i + 1], j2 = csr[i + 2], j3 = csr[i + 3];
                int j4 = csr[i + 4], j5 = csr[i + 5], j6 = csr[i + 6], j7 = csr[i + 7];
                unsigned int u0 = *(const unsigned int*)(base + (long long)j0 * SC + c2);
                unsigned int u1 = *(const unsigned int*)(base + (long long)j1 * SC + c2);
                unsigned int u2 = *(const unsigned int*)(base + (long long)j2 * SC + c2);
                unsigned int u3 = *(const unsigned int*)(base + (long long)j3 * SC + c2);
                unsigned int u4 = *(const unsigned int*)(base + (long long)j4 * SC + c2);
                unsigned int u5 = *(const unsigned int*)(base + (long long)j5 * SC + c2);
                unsigned int u6 = *(const unsigned int*)(base + (long long)j6 * SC + c2);
                unsigned int u7 = *(const unsigned int*)(base + (long long)j7 * SC + c2);
                s0 += ((b2f_lo(u0) + b2f_lo(u1)) + (b2f_lo(u2) + b2f_lo(u3)))
                    + ((b2f_lo(u4) + b2f_lo(u5)) + (b2f_lo(u6) + b2f_lo(u7)));
                s1 += ((b2f_hi(u0) + b2f_hi(u1)) + (b2f_hi(u2) + b2f_hi(u3)))
                    + ((b2f_hi(u4) + b2f_hi(u5)) + (b2f_hi(u6) + b2f_hi(u7)));
            }
            for (; i + 1 < end; i += 2) {
                int j0 = csr[i], j1 = csr[i + 1];
                unsigned int u0 = *(const unsigned int*)(base + (long long)j0 * SC + c2);
                unsigned int u1 = *(const unsigned int*)(base + (long long)j1 * SC + c2);
                s0 += b2f_lo(u0) + b2f_lo(u1);
                s1 += b2f_hi(u0) + b2f_hi(u1);
            }
            if (i < end) {
                unsigned int u0 = *(const unsigned int*)(base + (long long)csr[i] * SC + c2);
                s0 += b2f_lo(u0);
                s1 += b2f_hi(u0);
            }
            unsigned int uh = *(const unsigned int*)(base + (long long)node * SC + c2);
            float z0 = fmaf(e, b2f_lo(uh), s0);
            float z1 = fmaf(e, b2f_hi(uh), s1);
            *(unsigned int*)(Z + ((long long)node << 7) + s * SC + c2) =
                ((unsigned int)f2b(z1) << 16) | (unsigned int)f2b(z0);
        }
        __syncthreads();
    }
}

// ---------------- MFMA matmul (LDS-free, packed-B fragments) ----------------
template<int KIN, int KOUT, bool RELU, bool HASBIAS, bool OUTF32, bool OUTSLICED>
__global__ __launch_bounds__(256) void mm_mfma(
        const unsigned short* __restrict__ Zin, const unsigned short* __restrict__ Wp,
        const float* __restrict__ bias, void* __restrict__ outv, int Mreal, int Mp) {
    constexpr int KS = KIN / 32;
    constexpr int NT = KOUT / 16;
    const int tid = threadIdx.x;
    const int w = tid >> 6;
    const int l = tid & 63;
    const int lm = l & 15;
    const int lk = l >> 4;
    const long long arow = (long long)blockIdx.x * 64 + w * 16 + lm;
    const unsigned short* zrow = Zin + arow * KIN + lk * 8;

    float4v acc[NT];
#pragma unroll
    for (int t = 0; t < NT; ++t) acc[t] = (float4v){0.f, 0.f, 0.f, 0.f};

#pragma unroll
    for (int s = 0; s < KS; ++s) {
        short8 a = *(const short8*)(zrow + s * 32);
#pragma unroll
        for (int t = 0; t < NT; ++t) {
            short8 b = *(const short8*)(Wp + (long long)((t * KS + s) * 64 + l) * 8);
            acc[t] = __builtin_amdgcn_mfma_f32_16x16x32_bf16(a, b, acc[t], 0, 0, 0);
        }
    }

    const long long orow0 = (long long)blockIdx.x * 64 + w * 16 + lk * 4;
#pragma unroll
    for (int t = 0; t < NT; ++t) {
        const int n = t * 16 + lm;
        const float bv = HASBIAS ? bias[n] : 0.f;
#pragma unroll
        for (int r = 0; r < 4; ++r) {
            float v = acc[t][r] + bv;
            if (RELU) v = fmaxf(v, 0.f);
            const long long orow = orow0 + r;
            if (OUTF32) {
                if (orow < Mreal) ((float*)outv)[orow * KOUT + n] = v;
            } else if (OUTSLICED) {
                ((unsigned short*)outv)[((long long)(n >> 4) * Mp + orow) * SC + (n & 15)] = f2b(v);
            } else {
                ((unsigned short*)outv)[orow * KOUT + n] = f2b(v);
            }
        }
    }
}

extern "C" void kernel_launch(void* const* d_in, const int* in_sizes, int n_in,
                              void* d_out, int out_size, void* d_ws, size_t ws_size,
                              hipStream_t stream) {
    const float* x    = (const float*)d_in[0];
    const int*   ei   = (const int*)d_in[1];
    const float* Wemb = (const float*)d_in[2];
    const float* eps1 = (const float*)d_in[3];
    const float* w1a  = (const float*)d_in[4];
    const float* b1a  = (const float*)d_in[5];
    const float* w1b  = (const float*)d_in[6];
    const float* b1b  = (const float*)d_in[7];
    const float* eps2 = (const float*)d_in[8];
    const float* w2a  = (const float*)d_in[9];
    const float* b2a  = (const float*)d_in[10];
    const float* w2b  = (const float*)d_in[11];
    const float* b2b  = (const float*)d_in[12];
    const float* eps3 = (const float*)d_in[13];
    const float* w3a  = (const float*)d_in[14];
    const float* b3a  = (const float*)d_in[15];
    const float* w3b  = (const float*)d_in[16];
    const float* b3b  = (const float*)d_in[17];

    const int N = in_sizes[0] / 64;   // 100000
    const int E = in_sizes[1] / 2;    // 1600000
    const int Mpad = ((N + 63) / 64) * 64;
    const int NB = (N + BKT - 1) / BKT;
    const int G2 = 256;
    const int PB = (E + G2 - 1) / G2;
    const int BH = NB * G2;

    char* ws = (char*)d_ws;
    size_t off = 0;
    auto alloc = [&](size_t bytes) -> void* {
        void* p = ws + off;
        off = (off + bytes + 255) & ~(size_t)255;
        return p;
    };
    unsigned short* xb  = (unsigned short*)alloc((size_t)Mpad * 64 * 2);
    unsigned short* Hb  = (unsigned short*)alloc((size_t)Mpad * 128 * 2);  // slice-major
    unsigned short* Zb  = (unsigned short*)alloc((size_t)Mpad * 128 * 2);  // row-major
    unsigned short* Tb  = (unsigned short*)alloc((size_t)Mpad * 256 * 2);  // row-major
    unsigned short* pWe = (unsigned short*)alloc((size_t)64 * 128 * 2);
    unsigned short* p1a = (unsigned short*)alloc((size_t)128 * 128 * 2);
    unsigned short* p1b = (unsigned short*)alloc((size_t)128 * 128 * 2);
    unsigned short* p2a = (unsigned short*)alloc((size_t)128 * 256 * 2);
    unsigned short* p2b = (unsigned short*)alloc((size_t)256 * 128 * 2);
    unsigned short* p3a = (unsigned short*)alloc((size_t)128 * 256 * 2);
    unsigned short* p3b = (unsigned short*)alloc((size_t)256 * 128 * 2);
    int* offs = (int*)alloc((size_t)(N + 1) * 4);
    int* csr  = (int*)alloc((size_t)E * 4);
    int* bh   = (int*)alloc((size_t)BH * 4);
    int* bhs  = (int*)alloc((size_t)BH * 4);
    int* part = (int*)alloc(1024);
    int* boff = (int*)alloc(1024);
    int* flag = (int*)alloc(256);
    int* curs = (int*)alloc(3 * NS * 4);   // per-layer per-slice cursors

    // CSR staging aliased into Tb (first real use of Tb is the mm phase).
    unsigned int* staged = (unsigned int*)Tb;
    int* dsts = (int*)(Tb + (size_t)E * 2);
    int* srcs = (int*)(Tb + (size_t)E * 4);

    // ---- CSR build ----
    detect_i64_kernel<<<1, 64, 0, stream>>>((const unsigned int*)ei, flag);
    econv_kernel<<<(E + 255) / 256, 256, 0, stream>>>(ei, flag, srcs, dsts, E);
    part_hist_kernel<<<G2, 256, 0, stream>>>(dsts, bh, E, NB, PB);
    const int G1 = (BH + 1023) / 1024;
    scan1_kernel<<<G1, 1024, 0, stream>>>(bh, bhs, part, BH);
    scan2_kernel<<<1, 128, 0, stream>>>(part, boff, G1);
    scan3g_kernel<<<G1, 1024, 0, stream>>>(bhs, boff, BH);
    part_scatter_kernel<<<G2, 256, 0, stream>>>(dsts, srcs, bhs, staged, E, NB, PB);
    csr_local_kernel<<<NB, 256, 0, stream>>>(staged, bhs, offs, csr, N, E, NB, G2);

    // ---- conversions / weight packing / cursor init ----
    hipMemsetAsync(curs, 0, 3 * NS * 4, stream);
    xconv_kernel<<<(Mpad * 64 + 255) / 256, 256, 0, stream>>>(x, xb, N * 64, Mpad * 64);
    auto packw = [&](const float* W, unsigned short* o, int K, int KOUT) {
        int tot = (KOUT / 16) * (K / 32) * 64;
        packw_kernel<<<(tot + 255) / 256, 256, 0, stream>>>(W, o, K, KOUT);
    };
    packw(Wemb, pWe, 64, 128);
    packw(w1a, p1a, 128, 128);
    packw(w1b, p1b, 128, 128);
    packw(w2a, p2a, 128, 256);
    packw(w2b, p2b, 256, 128);
    packw(w3a, p3a, 128, 256);
    packw(w3b, p3b, 256, 128);

    const int MMB = Mpad / 64;
    const int AGB = 2048;   // persistent-ish blocks; work pulled via cursors

    // ---- embed: H = x @ W_embed (sliced output) ----
    mm_mfma<64, 128, false, false, false, true><<<MMB, 256, 0, stream>>>(xb, pWe, nullptr, Hb, N, Mpad);

    // ---- layer 1 ----
    aggz_xcd_kernel<<<AGB, 256, 0, stream>>>(Hb, offs, csr, eps1, Zb, curs + 0 * NS, N, Mpad);
    mm_mfma<128, 128, true,  true, false, false><<<MMB, 256, 0, stream>>>(Zb, p1a, b1a, Tb, N, Mpad);
    mm_mfma<128, 128, false, true, false, true ><<<MMB, 256, 0, stream>>>(Tb, p1b, b1b, Hb, N, Mpad);

    // ---- layer 2 ----
    aggz_xcd_kernel<<<AGB, 256, 0, stream>>>(Hb, offs, csr, eps2, Zb, curs + 1 * NS, N, Mpad);
    mm_mfma<128, 256, true, true, false, false><<<MMB, 256, 0, stream>>>(Zb, p2a, b2a, Tb, N, Mpad);
    mm_mfma<256, 128, true, true, false, true ><<<MMB, 256, 0, stream>>>(Tb, p2b, b2b, Hb, N, Mpad);

    // ---- layer 3 ----
    aggz_xcd_kernel<<<AGB, 256, 0, stream>>>(Hb, offs, csr, eps3, Zb, curs + 2 * NS, N, Mpad);
    mm_mfma<128, 256, true, true, false, false><<<MMB, 256, 0, stream>>>(Zb, p3a, b3a, Tb, N, Mpad);
    mm_mfma<256, 128, true, true, true, false><<<MMB, 256, 0, stream>>>(Tb, p3b, b3b, d_out, N, Mpad);
}

// Round 6
// 587.370 us; speedup vs baseline: 3.1612x; 3.1612x over previous
//
#include <hip/hip_runtime.h>
#include <hip/hip_bf16.h>
#include <stdint.h>

// ---------------------------------------------------------------------------
// GIN forward, round 6: row-major everything; aggregation gathers full 256 B
// node rows with dwordx4 (16 lanes/node x 16 B), unroll x4 => 4 KB in flight
// per wave (4x round-4 MLP). Radix-partition CSR, bf16 MFMA matmuls.
// ---------------------------------------------------------------------------

typedef __attribute__((ext_vector_type(8))) short short8;
typedef __attribute__((ext_vector_type(4))) float float4v;

#define BKT 512       // nodes per bucket (dst >> 9)
#define NBMAX 256     // max buckets held in LDS (NB = 196 here)

__device__ __forceinline__ float b2f_lo(unsigned int u) {
    return __uint_as_float(u << 16);
}
__device__ __forceinline__ float b2f_hi(unsigned int u) {
    return __uint_as_float(u & 0xffff0000u);
}
__device__ __forceinline__ unsigned short f2b(float f) {
    unsigned int u = __float_as_uint(f);
    return (unsigned short)((u + 0x7fffu + ((u >> 16) & 1u)) >> 16);  // RNE
}

// ---------------- edge-index dtype detection ----------------
__global__ void detect_i64_kernel(const unsigned int* ei, int* flag) {
    if (threadIdx.x == 0) {
        int is64 = 1;
        for (int e = 0; e < 64; ++e)
            if (ei[2 * e + 1] != 0u) { is64 = 0; break; }
        *flag = is64;
    }
}

__device__ __forceinline__ int edge_at(const int* ei32, int is64, long long pos) {
    if (is64) return (int)(((const long long*)ei32)[pos]);
    return ei32[pos];
}

// unpack edge_index into src/dst i32 arrays (coalesced)
__global__ void econv_kernel(const int* __restrict__ ei, const int* __restrict__ flag,
                             int* __restrict__ srcs, int* __restrict__ dsts, int E) {
    int e = blockIdx.x * blockDim.x + threadIdx.x;
    if (e >= E) return;
    int is64 = *flag;
    srcs[e] = edge_at(ei, is64, e);
    dsts[e] = edge_at(ei, is64, (long long)E + e);
}

// ---------------- radix partition pass 1: per-(block,bucket) histogram ----------------
__global__ __launch_bounds__(256) void part_hist_kernel(
        const int* __restrict__ dsts, int* __restrict__ bh, int E, int NB, int PB) {
    __shared__ int h[NBMAX];
    const int g = blockIdx.x, tid = threadIdx.x;
    for (int i = tid; i < NB; i += 256) h[i] = 0;
    __syncthreads();
    const int e0 = g * PB, e1 = min(e0 + PB, E);
    for (int e = e0 + tid; e < e1; e += 256)
        atomicAdd(&h[dsts[e] >> 9], 1);
    __syncthreads();
    for (int i = tid; i < NB; i += 256) bh[i * gridDim.x + g] = h[i];
}

// ---------------- generic multi-block exclusive scan ----------------
__global__ __launch_bounds__(1024) void scan1_kernel(
        const int* __restrict__ in, int* __restrict__ out,
        int* __restrict__ partial, int n) {
    __shared__ int sm[1024];
    const int t = threadIdx.x;
    const int i = blockIdx.x * 1024 + t;
    int v = (i < n) ? in[i] : 0;
    sm[t] = v;
    __syncthreads();
#pragma unroll
    for (int off = 1; off < 1024; off <<= 1) {
        int x = (t >= off) ? sm[t - off] : 0;
        __syncthreads();
        sm[t] += x;
        __syncthreads();
    }
    if (i < n) out[i] = sm[t] - v;
    if (t == 1023) partial[blockIdx.x] = sm[1023];
}

__global__ __launch_bounds__(128) void scan2_kernel(
        int* __restrict__ partial, int* __restrict__ blockoff, int g1) {
    __shared__ int sm[128];
    const int t = threadIdx.x;
    int v = (t < g1) ? partial[t] : 0;
    sm[t] = v;
    __syncthreads();
#pragma unroll
    for (int off = 1; off < 128; off <<= 1) {
        int x = (t >= off) ? sm[t - off] : 0;
        __syncthreads();
        sm[t] += x;
        __syncthreads();
    }
    blockoff[t] = sm[t] - v;
}

__global__ __launch_bounds__(1024) void scan3g_kernel(
        int* __restrict__ a, const int* __restrict__ blockoff, int n) {
    int i = blockIdx.x * 1024 + threadIdx.x;
    if (i < n) a[i] += blockoff[blockIdx.x];
}

// ---------------- pass 2: scatter edges into bucket-contiguous staging ----------------
// staged entry: (dlocal<<17) | src
__global__ __launch_bounds__(256) void part_scatter_kernel(
        const int* __restrict__ dsts, const int* __restrict__ srcs,
        const int* __restrict__ bhs, unsigned int* __restrict__ staged,
        int E, int NB, int PB) {
    __shared__ int cur[NBMAX];
    const int g = blockIdx.x, tid = threadIdx.x;
    for (int i = tid; i < NB; i += 256) cur[i] = bhs[i * gridDim.x + g];
    __syncthreads();
    const int e0 = g * PB, e1 = min(e0 + PB, E);
    for (int e = e0 + tid; e < e1; e += 256) {
        int d = dsts[e];
        int s = srcs[e];
        int b = d >> 9;
        int p = atomicAdd(&cur[b], 1);
        staged[p] = ((unsigned int)(d & (BKT - 1)) << 17) | (unsigned int)s;
    }
}

// ---------------- pass 3: per-bucket counting sort -> offs + csr ----------------
__global__ __launch_bounds__(256) void csr_local_kernel(
        const unsigned int* __restrict__ staged, const int* __restrict__ bhs,
        int* __restrict__ offs, int* __restrict__ csr, int N, int E, int NB, int G2) {
    __shared__ int hist[BKT];
    __shared__ int cur[BKT];
    const int b = blockIdx.x;
    const int tid = threadIdx.x;
    const int start = bhs[b * G2];
    const int end = (b + 1 < NB) ? bhs[(b + 1) * G2] : E;
    const int node0 = b * BKT;
    for (int i = tid; i < BKT; i += 256) hist[i] = 0;
    __syncthreads();
    for (int i = start + tid; i < end; i += 256)
        atomicAdd(&hist[staged[i] >> 17], 1);
    __syncthreads();
    const int i0 = tid * 2, i1 = i0 + 1;
    for (int off = 1; off < BKT; off <<= 1) {
        int v0 = (i0 >= off) ? hist[i0 - off] : 0;
        int v1 = (i1 >= off) ? hist[i1 - off] : 0;
        __syncthreads();
        hist[i0] += v0;
        hist[i1] += v1;
        __syncthreads();
    }
    for (int i = tid; i < BKT; i += 256) {
        int node = node0 + i;
        if (node < N) {
            int e0 = start + ((i == 0) ? 0 : hist[i - 1]);
            offs[node] = e0;
            cur[i] = e0;
        }
    }
    if (b == NB - 1 && tid == 0) offs[N] = E;
    __syncthreads();
    for (int i = start + tid; i < end; i += 256) {
        unsigned int v = staged[i];
        int dl = v >> 17;
        int src = (int)(v & 0x1ffff);
        int p = atomicAdd(&cur[dl], 1);
        csr[p] = src;
    }
}

// ---------------- conversions ----------------
__global__ void xconv_kernel(const float* __restrict__ x, unsigned short* __restrict__ xb,
                             int total_real, int total_pad) {
    int i = blockIdx.x * blockDim.x + threadIdx.x;
    if (i >= total_pad) return;
    xb[i] = (i < total_real) ? f2b(x[i]) : (unsigned short)0;
}

// Pack W[K x KOUT] (f32 row-major) into MFMA-B fragment order.
__global__ void packw_kernel(const float* __restrict__ W, unsigned short* __restrict__ out,
                             int K, int KOUT) {
    const int KS = K / 32;
    const int total = (KOUT / 16) * KS * 64;
    int id = blockIdx.x * blockDim.x + threadIdx.x;
    if (id >= total) return;
    const int l = id & 63;
    const int s = (id >> 6) % KS;
    const int t = id / (KS * 64);
    const int kbase = s * 32 + ((l >> 4) << 3);
    const int n = t * 16 + (l & 15);
#pragma unroll
    for (int j = 0; j < 8; ++j)
        out[(long long)id * 8 + j] = f2b(W[(long long)(kbase + j) * KOUT + n]);
}

// ---------------- aggregation: Z = (1+eps)*H + sum_{j in N(i)} H[j] ----------------
// Row-major bf16 H (128 cols = 256 B rows). 16 lanes per node, 16 B (8 cols)
// per lane via dwordx4; neighbor loop unrolled x4 => 4 outstanding 16 B
// loads/lane = 4 KB in flight per wave. 256 threads = 16 nodes/block.
__global__ __launch_bounds__(256) void aggz_kernel(
        const unsigned short* __restrict__ H, const int* __restrict__ offs,
        const int* __restrict__ csr, const float* __restrict__ eps,
        unsigned short* __restrict__ Z, int n) {
    const int node = blockIdx.x * 16 + (threadIdx.x >> 4);
    const int c8 = (threadIdx.x & 15) << 3;   // 8-col group base
    if (node >= n) return;
    const int beg = offs[node];
    const int end = offs[node + 1];
    float a0 = 0.f, a1 = 0.f, a2 = 0.f, a3 = 0.f;
    float a4 = 0.f, a5 = 0.f, a6 = 0.f, a7 = 0.f;
    int i = beg;
    for (; i + 3 < end; i += 4) {
        const int j0 = csr[i], j1 = csr[i + 1], j2 = csr[i + 2], j3 = csr[i + 3];
        const uint4 u0 = *(const uint4*)(H + ((long long)j0 << 7) + c8);
        const uint4 u1 = *(const uint4*)(H + ((long long)j1 << 7) + c8);
        const uint4 u2 = *(const uint4*)(H + ((long long)j2 << 7) + c8);
        const uint4 u3 = *(const uint4*)(H + ((long long)j3 << 7) + c8);
        a0 += (b2f_lo(u0.x) + b2f_lo(u1.x)) + (b2f_lo(u2.x) + b2f_lo(u3.x));
        a1 += (b2f_hi(u0.x) + b2f_hi(u1.x)) + (b2f_hi(u2.x) + b2f_hi(u3.x));
        a2 += (b2f_lo(u0.y) + b2f_lo(u1.y)) + (b2f_lo(u2.y) + b2f_lo(u3.y));
        a3 += (b2f_hi(u0.y) + b2f_hi(u1.y)) + (b2f_hi(u2.y) + b2f_hi(u3.y));
        a4 += (b2f_lo(u0.z) + b2f_lo(u1.z)) + (b2f_lo(u2.z) + b2f_lo(u3.z));
        a5 += (b2f_hi(u0.z) + b2f_hi(u1.z)) + (b2f_hi(u2.z) + b2f_hi(u3.z));
        a6 += (b2f_lo(u0.w) + b2f_lo(u1.w)) + (b2f_lo(u2.w) + b2f_lo(u3.w));
        a7 += (b2f_hi(u0.w) + b2f_hi(u1.w)) + (b2f_hi(u2.w) + b2f_hi(u3.w));
    }
    for (; i < end; ++i) {
        const int j0 = csr[i];
        const uint4 u0 = *(const uint4*)(H + ((long long)j0 << 7) + c8);
        a0 += b2f_lo(u0.x); a1 += b2f_hi(u0.x);
        a2 += b2f_lo(u0.y); a3 += b2f_hi(u0.y);
        a4 += b2f_lo(u0.z); a5 += b2f_hi(u0.z);
        a6 += b2f_lo(u0.w); a7 += b2f_hi(u0.w);
    }
    const uint4 uh = *(const uint4*)(H + ((long long)node << 7) + c8);
    const float e = 1.0f + eps[0];
    a0 = fmaf(e, b2f_lo(uh.x), a0); a1 = fmaf(e, b2f_hi(uh.x), a1);
    a2 = fmaf(e, b2f_lo(uh.y), a2); a3 = fmaf(e, b2f_hi(uh.y), a3);
    a4 = fmaf(e, b2f_lo(uh.z), a4); a5 = fmaf(e, b2f_hi(uh.z), a5);
    a6 = fmaf(e, b2f_lo(uh.w), a6); a7 = fmaf(e, b2f_hi(uh.w), a7);
    uint4 o;
    o.x = ((unsigned int)f2b(a1) << 16) | (unsigned int)f2b(a0);
    o.y = ((unsigned int)f2b(a3) << 16) | (unsigned int)f2b(a2);
    o.z = ((unsigned int)f2b(a5) << 16) | (unsigned int)f2b(a4);
    o.w = ((unsigned int)f2b(a7) << 16) | (unsigned int)f2b(a6);
    *(uint4*)(Z + ((long long)node << 7) + c8) = o;
}

// ---------------- MFMA matmul (LDS-free, packed-B fragments) ----------------
template<int KIN, int KOUT, bool RELU, bool HASBIAS, bool OUTF32>
__global__ __launch_bounds__(256) void mm_mfma(
        const unsigned short* __restrict__ Zin, const unsigned short* __restrict__ Wp,
        const float* __restrict__ bias, void* __restrict__ outv, int Mreal) {
    constexpr int KS = KIN / 32;
    constexpr int NT = KOUT / 16;
    const int tid = threadIdx.x;
    const int w = tid >> 6;
    const int l = tid & 63;
    const int lm = l & 15;
    const int lk = l >> 4;
    const long long arow = (long long)blockIdx.x * 64 + w * 16 + lm;
    const unsigned short* zrow = Zin + arow * KIN + lk * 8;

    float4v acc[NT];
#pragma unroll
    for (int t = 0; t < NT; ++t) acc[t] = (float4v){0.f, 0.f, 0.f, 0.f};

#pragma unroll
    for (int s = 0; s < KS; ++s) {
        short8 a = *(const short8*)(zrow + s * 32);
#pragma unroll
        for (int t = 0; t < NT; ++t) {
            short8 b = *(const short8*)(Wp + (long long)((t * KS + s) * 64 + l) * 8);
            acc[t] = __builtin_amdgcn_mfma_f32_16x16x32_bf16(a, b, acc[t], 0, 0, 0);
        }
    }

    const long long orow0 = (long long)blockIdx.x * 64 + w * 16 + lk * 4;
#pragma unroll
    for (int t = 0; t < NT; ++t) {
        const int n = t * 16 + lm;
        const float bv = HASBIAS ? bias[n] : 0.f;
#pragma unroll
        for (int r = 0; r < 4; ++r) {
            float v = acc[t][r] + bv;
            if (RELU) v = fmaxf(v, 0.f);
            const long long orow = orow0 + r;
            if (OUTF32) {
                if (orow < Mreal) ((float*)outv)[orow * KOUT + n] = v;
            } else {
                ((unsigned short*)outv)[orow * KOUT + n] = f2b(v);
            }
        }
    }
}

extern "C" void kernel_launch(void* const* d_in, const int* in_sizes, int n_in,
                              void* d_out, int out_size, void* d_ws, size_t ws_size,
                              hipStream_t stream) {
    const float* x    = (const float*)d_in[0];
    const int*   ei   = (const int*)d_in[1];
    const float* Wemb = (const float*)d_in[2];
    const float* eps1 = (const float*)d_in[3];
    const float* w1a  = (const float*)d_in[4];
    const float* b1a  = (const float*)d_in[5];
    const float* w1b  = (const float*)d_in[6];
    const float* b1b  = (const float*)d_in[7];
    const float* eps2 = (const float*)d_in[8];
    const float* w2a  = (const float*)d_in[9];
    const float* b2a  = (const float*)d_in[10];
    const float* w2b  = (const float*)d_in[11];
    const float* b2b  = (const float*)d_in[12];
    const float* eps3 = (const float*)d_in[13];
    const float* w3a  = (const float*)d_in[14];
    const float* b3a  = (const float*)d_in[15];
    const float* w3b  = (const float*)d_in[16];
    const float* b3b  = (const float*)d_in[17];

    const int N = in_sizes[0] / 64;   // 100000
    const int E = in_sizes[1] / 2;    // 1600000
    const int Mpad = ((N + 63) / 64) * 64;
    const int NB = (N + BKT - 1) / BKT;   // 196
    const int G2 = 256;
    const int PB = (E + G2 - 1) / G2;
    const int BH = NB * G2;

    char* ws = (char*)d_ws;
    size_t off = 0;
    auto alloc = [&](size_t bytes) -> void* {
        void* p = ws + off;
        off = (off + bytes + 255) & ~(size_t)255;
        return p;
    };
    unsigned short* xb  = (unsigned short*)alloc((size_t)Mpad * 64 * 2);
    unsigned short* Hb  = (unsigned short*)alloc((size_t)Mpad * 128 * 2);
    unsigned short* Zb  = (unsigned short*)alloc((size_t)Mpad * 128 * 2);
    unsigned short* Tb  = (unsigned short*)alloc((size_t)Mpad * 256 * 2);
    unsigned short* pWe = (unsigned short*)alloc((size_t)64 * 128 * 2);
    unsigned short* p1a = (unsigned short*)alloc((size_t)128 * 128 * 2);
    unsigned short* p1b = (unsigned short*)alloc((size_t)128 * 128 * 2);
    unsigned short* p2a = (unsigned short*)alloc((size_t)128 * 256 * 2);
    unsigned short* p2b = (unsigned short*)alloc((size_t)256 * 128 * 2);
    unsigned short* p3a = (unsigned short*)alloc((size_t)128 * 256 * 2);
    unsigned short* p3b = (unsigned short*)alloc((size_t)256 * 128 * 2);
    int* offs = (int*)alloc((size_t)(N + 1) * 4);
    int* csr  = (int*)alloc((size_t)E * 4);
    int* bh   = (int*)alloc((size_t)BH * 4);
    int* bhs  = (int*)alloc((size_t)BH * 4);
    int* part = (int*)alloc(1024);
    int* boff = (int*)alloc(1024);
    int* flag = (int*)alloc(256);

    // CSR staging aliased into Tb (first real use of Tb is the mm phase).
    unsigned int* staged = (unsigned int*)Tb;
    int* dsts = (int*)(Tb + (size_t)E * 2);
    int* srcs = (int*)(Tb + (size_t)E * 4);

    // ---- CSR build ----
    detect_i64_kernel<<<1, 64, 0, stream>>>((const unsigned int*)ei, flag);
    econv_kernel<<<(E + 255) / 256, 256, 0, stream>>>(ei, flag, srcs, dsts, E);
    part_hist_kernel<<<G2, 256, 0, stream>>>(dsts, bh, E, NB, PB);
    const int G1 = (BH + 1023) / 1024;
    scan1_kernel<<<G1, 1024, 0, stream>>>(bh, bhs, part, BH);
    scan2_kernel<<<1, 128, 0, stream>>>(part, boff, G1);
    scan3g_kernel<<<G1, 1024, 0, stream>>>(bhs, boff, BH);
    part_scatter_kernel<<<G2, 256, 0, stream>>>(dsts, srcs, bhs, staged, E, NB, PB);
    csr_local_kernel<<<NB, 256, 0, stream>>>(staged, bhs, offs, csr, N, E, NB, G2);

    // ---- conversions / weight packing ----
    xconv_kernel<<<(Mpad * 64 + 255) / 256, 256, 0, stream>>>(x, xb, N * 64, Mpad * 64);
    auto packw = [&](const float* W, unsigned short* o, int K, int KOUT) {
        int tot = (KOUT / 16) * (K / 32) * 64;
        packw_kernel<<<(tot + 255) / 256, 256, 0, stream>>>(W, o, K, KOUT);
    };
    packw(Wemb, pWe, 64, 128);
    packw(w1a, p1a, 128, 128);
    packw(w1b, p1b, 128, 128);
    packw(w2a, p2a, 128, 256);
    packw(w2b, p2b, 256, 128);
    packw(w3a, p3a, 128, 256);
    packw(w3b, p3b, 256, 128);

    const int MMB = Mpad / 64;
    const int AGB = (N + 15) / 16;   // 16 nodes per block

    // ---- embed: H = x @ W_embed ----
    mm_mfma<64, 128, false, false, false><<<MMB, 256, 0, stream>>>(xb, pWe, nullptr, Hb, N);

    // ---- layer 1 ----
    aggz_kernel<<<AGB, 256, 0, stream>>>(Hb, offs, csr, eps1, Zb, N);
    mm_mfma<128, 128, true,  true, false><<<MMB, 256, 0, stream>>>(Zb, p1a, b1a, Tb, N);
    mm_mfma<128, 128, false, true, false><<<MMB, 256, 0, stream>>>(Tb, p1b, b1b, Hb, N);

    // ---- layer 2 ----
    aggz_kernel<<<AGB, 256, 0, stream>>>(Hb, offs, csr, eps2, Zb, N);
    mm_mfma<128, 256, true, true, false><<<MMB, 256, 0, stream>>>(Zb, p2a, b2a, Tb, N);
    mm_mfma<256, 128, true, true, false><<<MMB, 256, 0, stream>>>(Tb, p2b, b2b, Hb, N);

    // ---- layer 3 ----
    aggz_kernel<<<AGB, 256, 0, stream>>>(Hb, offs, csr, eps3, Zb, N);
    mm_mfma<128, 256, true, true, false><<<MMB, 256, 0, stream>>>(Zb, p3a, b3a, Tb, N);
    mm_mfma<256, 128, true, true, true><<<MMB, 256, 0, stream>>>(Tb, p3b, b3b, d_out, N);
}

// Round 7
// 586.014 us; speedup vs baseline: 3.1686x; 1.0023x over previous
//
#include <hip/hip_runtime.h>
#include <hip/hip_bf16.h>
#include <stdint.h>

// ---------------------------------------------------------------------------
// GIN forward, round 7: aggz unroll x8 (8 KB in flight per wave), econv
// folded into partition kernels, single fused weight-pack dispatch.
// Radix-partition CSR, bf16 MFMA matmuls.
// ---------------------------------------------------------------------------

typedef __attribute__((ext_vector_type(8))) short short8;
typedef __attribute__((ext_vector_type(4))) float float4v;

#define BKT 512       // nodes per bucket (dst >> 9)
#define NBMAX 256     // max buckets held in LDS (NB = 196 here)

__device__ __forceinline__ float b2f_lo(unsigned int u) {
    return __uint_as_float(u << 16);
}
__device__ __forceinline__ float b2f_hi(unsigned int u) {
    return __uint_as_float(u & 0xffff0000u);
}
__device__ __forceinline__ unsigned short f2b(float f) {
    unsigned int u = __float_as_uint(f);
    return (unsigned short)((u + 0x7fffu + ((u >> 16) & 1u)) >> 16);  // RNE
}

// ---------------- edge-index dtype detection ----------------
__global__ void detect_i64_kernel(const unsigned int* ei, int* flag) {
    if (threadIdx.x == 0) {
        int is64 = 1;
        for (int e = 0; e < 64; ++e)
            if (ei[2 * e + 1] != 0u) { is64 = 0; break; }
        *flag = is64;
    }
}

__device__ __forceinline__ int edge_at(const int* ei32, int is64, long long pos) {
    if (is64) return (int)(((const long long*)ei32)[pos]);
    return ei32[pos];
}

// ---------------- radix partition pass 1: per-(block,bucket) histogram ----------------
// reads dst half of edge_index directly
__global__ __launch_bounds__(256) void part_hist_kernel(
        const int* __restrict__ ei, const int* __restrict__ flag,
        int* __restrict__ bh, int E, int NB, int PB) {
    __shared__ int h[NBMAX];
    const int g = blockIdx.x, tid = threadIdx.x;
    const int is64 = *flag;
    for (int i = tid; i < NB; i += 256) h[i] = 0;
    __syncthreads();
    const int e0 = g * PB, e1 = min(e0 + PB, E);
    for (int e = e0 + tid; e < e1; e += 256) {
        int d = edge_at(ei, is64, (long long)E + e);
        atomicAdd(&h[d >> 9], 1);
    }
    __syncthreads();
    for (int i = tid; i < NB; i += 256) bh[i * gridDim.x + g] = h[i];
}

// ---------------- generic multi-block exclusive scan ----------------
__global__ __launch_bounds__(1024) void scan1_kernel(
        const int* __restrict__ in, int* __restrict__ out,
        int* __restrict__ partial, int n) {
    __shared__ int sm[1024];
    const int t = threadIdx.x;
    const int i = blockIdx.x * 1024 + t;
    int v = (i < n) ? in[i] : 0;
    sm[t] = v;
    __syncthreads();
#pragma unroll
    for (int off = 1; off < 1024; off <<= 1) {
        int x = (t >= off) ? sm[t - off] : 0;
        __syncthreads();
        sm[t] += x;
        __syncthreads();
    }
    if (i < n) out[i] = sm[t] - v;
    if (t == 1023) partial[blockIdx.x] = sm[1023];
}

__global__ __launch_bounds__(128) void scan2_kernel(
        int* __restrict__ partial, int* __restrict__ blockoff, int g1) {
    __shared__ int sm[128];
    const int t = threadIdx.x;
    int v = (t < g1) ? partial[t] : 0;
    sm[t] = v;
    __syncthreads();
#pragma unroll
    for (int off = 1; off < 128; off <<= 1) {
        int x = (t >= off) ? sm[t - off] : 0;
        __syncthreads();
        sm[t] += x;
        __syncthreads();
    }
    blockoff[t] = sm[t] - v;
}

__global__ __launch_bounds__(1024) void scan3g_kernel(
        int* __restrict__ a, const int* __restrict__ blockoff, int n) {
    int i = blockIdx.x * 1024 + threadIdx.x;
    if (i < n) a[i] += blockoff[blockIdx.x];
}

// ---------------- pass 2: scatter edges into bucket-contiguous staging ----------------
// staged entry: (dlocal<<17) | src ; reads edge_index directly
__global__ __launch_bounds__(256) void part_scatter_kernel(
        const int* __restrict__ ei, const int* __restrict__ flag,
        const int* __restrict__ bhs, unsigned int* __restrict__ staged,
        int E, int NB, int PB) {
    __shared__ int cur[NBMAX];
    const int g = blockIdx.x, tid = threadIdx.x;
    const int is64 = *flag;
    for (int i = tid; i < NB; i += 256) cur[i] = bhs[i * gridDim.x + g];
    __syncthreads();
    const int e0 = g * PB, e1 = min(e0 + PB, E);
    for (int e = e0 + tid; e < e1; e += 256) {
        int d = edge_at(ei, is64, (long long)E + e);
        int s = edge_at(ei, is64, (long long)e);
        int b = d >> 9;
        int p = atomicAdd(&cur[b], 1);
        staged[p] = ((unsigned int)(d & (BKT - 1)) << 17) | (unsigned int)s;
    }
}

// ---------------- pass 3: per-bucket counting sort -> offs + csr ----------------
__global__ __launch_bounds__(256) void csr_local_kernel(
        const unsigned int* __restrict__ staged, const int* __restrict__ bhs,
        int* __restrict__ offs, int* __restrict__ csr, int N, int E, int NB, int G2) {
    __shared__ int hist[BKT];
    __shared__ int cur[BKT];
    const int b = blockIdx.x;
    const int tid = threadIdx.x;
    const int start = bhs[b * G2];
    const int end = (b + 1 < NB) ? bhs[(b + 1) * G2] : E;
    const int node0 = b * BKT;
    for (int i = tid; i < BKT; i += 256) hist[i] = 0;
    __syncthreads();
    for (int i = start + tid; i < end; i += 256)
        atomicAdd(&hist[staged[i] >> 17], 1);
    __syncthreads();
    const int i0 = tid * 2, i1 = i0 + 1;
    for (int off = 1; off < BKT; off <<= 1) {
        int v0 = (i0 >= off) ? hist[i0 - off] : 0;
        int v1 = (i1 >= off) ? hist[i1 - off] : 0;
        __syncthreads();
        hist[i0] += v0;
        hist[i1] += v1;
        __syncthreads();
    }
    for (int i = tid; i < BKT; i += 256) {
        int node = node0 + i;
        if (node < N) {
            int e0 = start + ((i == 0) ? 0 : hist[i - 1]);
            offs[node] = e0;
            cur[i] = e0;
        }
    }
    if (b == NB - 1 && tid == 0) offs[N] = E;
    __syncthreads();
    for (int i = start + tid; i < end; i += 256) {
        unsigned int v = staged[i];
        int dl = v >> 17;
        int src = (int)(v & 0x1ffff);
        int p = atomicAdd(&cur[dl], 1);
        csr[p] = src;
    }
}

// ---------------- conversions ----------------
__global__ void xconv_kernel(const float* __restrict__ x, unsigned short* __restrict__ xb,
                             int total_real, int total_pad) {
    int i = blockIdx.x * blockDim.x + threadIdx.x;
    if (i >= total_pad) return;
    xb[i] = (i < total_real) ? f2b(x[i]) : (unsigned short)0;
}

// Fused weight pack: all 7 weights in one dispatch.
// out[(((t*KS + s)*64 + l)*8 + j] = bf16(W[(s*32 + (l>>4)*8 + j)*KOUT + t*16 + (l&15)])
struct PW { const float* W; unsigned short* o; int K; int KOUT; };
struct PWAll { PW d[7]; int cum[8]; };

__global__ __launch_bounds__(256) void packall_kernel(PWAll P) {
    int id = blockIdx.x * blockDim.x + threadIdx.x;
    if (id >= P.cum[7]) return;
    int w = 0;
#pragma unroll
    for (int k = 1; k < 7; ++k) w += (id >= P.cum[k]);
    const int local = id - P.cum[w];
    const float* W = P.d[w].W;
    unsigned short* out = P.d[w].o;
    const int K = P.d[w].K, KOUT = P.d[w].KOUT;
    const int KS = K / 32;
    const int l = local & 63;
    const int s = (local >> 6) % KS;
    const int t = local / (KS * 64);
    const int kbase = s * 32 + ((l >> 4) << 3);
    const int n = t * 16 + (l & 15);
#pragma unroll
    for (int j = 0; j < 8; ++j)
        out[(long long)local * 8 + j] = f2b(W[(long long)(kbase + j) * KOUT + n]);
}

// ---------------- aggregation: Z = (1+eps)*H + sum_{j in N(i)} H[j] ----------------
// Row-major bf16 H (128 cols = 256 B rows). 16 lanes/node, 16 B/lane dwordx4;
// unroll x8 => 8 outstanding 16 B loads/lane = 8 KB in flight per wave.
__global__ __launch_bounds__(256) void aggz_kernel(
        const unsigned short* __restrict__ H, const int* __restrict__ offs,
        const int* __restrict__ csr, const float* __restrict__ eps,
        unsigned short* __restrict__ Z, int n) {
    const int node = blockIdx.x * 16 + (threadIdx.x >> 4);
    const int c8 = (threadIdx.x & 15) << 3;   // 8-col group base
    if (node >= n) return;
    const int beg = offs[node];
    const int end = offs[node + 1];
    float a0 = 0.f, a1 = 0.f, a2 = 0.f, a3 = 0.f;
    float a4 = 0.f, a5 = 0.f, a6 = 0.f, a7 = 0.f;
    int i = beg;
    for (; i + 7 < end; i += 8) {
        const int j0 = csr[i],     j1 = csr[i + 1], j2 = csr[i + 2], j3 = csr[i + 3];
        const int j4 = csr[i + 4], j5 = csr[i + 5], j6 = csr[i + 6], j7 = csr[i + 7];
        const uint4 u0 = *(const uint4*)(H + ((long long)j0 << 7) + c8);
        const uint4 u1 = *(const uint4*)(H + ((long long)j1 << 7) + c8);
        const uint4 u2 = *(const uint4*)(H + ((long long)j2 << 7) + c8);
        const uint4 u3 = *(const uint4*)(H + ((long long)j3 << 7) + c8);
        const uint4 u4 = *(const uint4*)(H + ((long long)j4 << 7) + c8);
        const uint4 u5 = *(const uint4*)(H + ((long long)j5 << 7) + c8);
        const uint4 u6 = *(const uint4*)(H + ((long long)j6 << 7) + c8);
        const uint4 u7 = *(const uint4*)(H + ((long long)j7 << 7) + c8);
        a0 += ((b2f_lo(u0.x) + b2f_lo(u1.x)) + (b2f_lo(u2.x) + b2f_lo(u3.x)))
            + ((b2f_lo(u4.x) + b2f_lo(u5.x)) + (b2f_lo(u6.x) + b2f_lo(u7.x)));
        a1 += ((b2f_hi(u0.x) + b2f_hi(u1.x)) + (b2f_hi(u2.x) + b2f_hi(u3.x)))
            + ((b2f_hi(u4.x) + b2f_hi(u5.x)) + (b2f_hi(u6.x) + b2f_hi(u7.x)));
        a2 += ((b2f_lo(u0.y) + b2f_lo(u1.y)) + (b2f_lo(u2.y) + b2f_lo(u3.y)))
            + ((b2f_lo(u4.y) + b2f_lo(u5.y)) + (b2f_lo(u6.y) + b2f_lo(u7.y)));
        a3 += ((b2f_hi(u0.y) + b2f_hi(u1.y)) + (b2f_hi(u2.y) + b2f_hi(u3.y)))
            + ((b2f_hi(u4.y) + b2f_hi(u5.y)) + (b2f_hi(u6.y) + b2f_hi(u7.y)));
        a4 += ((b2f_lo(u0.z) + b2f_lo(u1.z)) + (b2f_lo(u2.z) + b2f_lo(u3.z)))
            + ((b2f_lo(u4.z) + b2f_lo(u5.z)) + (b2f_lo(u6.z) + b2f_lo(u7.z)));
        a5 += ((b2f_hi(u0.z) + b2f_hi(u1.z)) + (b2f_hi(u2.z) + b2f_hi(u3.z)))
            + ((b2f_hi(u4.z) + b2f_hi(u5.z)) + (b2f_hi(u6.z) + b2f_hi(u7.z)));
        a6 += ((b2f_lo(u0.w) + b2f_lo(u1.w)) + (b2f_lo(u2.w) + b2f_lo(u3.w)))
            + ((b2f_lo(u4.w) + b2f_lo(u5.w)) + (b2f_lo(u6.w) + b2f_lo(u7.w)));
        a7 += ((b2f_hi(u0.w) + b2f_hi(u1.w)) + (b2f_hi(u2.w) + b2f_hi(u3.w)))
            + ((b2f_hi(u4.w) + b2f_hi(u5.w)) + (b2f_hi(u6.w) + b2f_hi(u7.w)));
    }
    for (; i + 3 < end; i += 4) {
        const int j0 = csr[i], j1 = csr[i + 1], j2 = csr[i + 2], j3 = csr[i + 3];
        const uint4 u0 = *(const uint4*)(H + ((long long)j0 << 7) + c8);
        const uint4 u1 = *(const uint4*)(H + ((long long)j1 << 7) + c8);
        const uint4 u2 = *(const uint4*)(H + ((long long)j2 << 7) + c8);
        const uint4 u3 = *(const uint4*)(H + ((long long)j3 << 7) + c8);
        a0 += (b2f_lo(u0.x) + b2f_lo(u1.x)) + (b2f_lo(u2.x) + b2f_lo(u3.x));
        a1 += (b2f_hi(u0.x) + b2f_hi(u1.x)) + (b2f_hi(u2.x) + b2f_hi(u3.x));
        a2 += (b2f_lo(u0.y) + b2f_lo(u1.y)) + (b2f_lo(u2.y) + b2f_lo(u3.y));
        a3 += (b2f_hi(u0.y) + b2f_hi(u1.y)) + (b2f_hi(u2.y) + b2f_hi(u3.y));
        a4 += (b2f_lo(u0.z) + b2f_lo(u1.z)) + (b2f_lo(u2.z) + b2f_lo(u3.z));
        a5 += (b2f_hi(u0.z) + b2f_hi(u1.z)) + (b2f_hi(u2.z) + b2f_hi(u3.z));
        a6 += (b2f_lo(u0.w) + b2f_lo(u1.w)) + (b2f_lo(u2.w) + b2f_lo(u3.w));
        a7 += (b2f_hi(u0.w) + b2f_hi(u1.w)) + (b2f_hi(u2.w) + b2f_hi(u3.w));
    }
    for (; i < end; ++i) {
        const int j0 = csr[i];
        const uint4 u0 = *(const uint4*)(H + ((long long)j0 << 7) + c8);
        a0 += b2f_lo(u0.x); a1 += b2f_hi(u0.x);
        a2 += b2f_lo(u0.y); a3 += b2f_hi(u0.y);
        a4 += b2f_lo(u0.z); a5 += b2f_hi(u0.z);
        a6 += b2f_lo(u0.w); a7 += b2f_hi(u0.w);
    }
    const uint4 uh = *(const uint4*)(H + ((long long)node << 7) + c8);
    const float e = 1.0f + eps[0];
    a0 = fmaf(e, b2f_lo(uh.x), a0); a1 = fmaf(e, b2f_hi(uh.x), a1);
    a2 = fmaf(e, b2f_lo(uh.y), a2); a3 = fmaf(e, b2f_hi(uh.y), a3);
    a4 = fmaf(e, b2f_lo(uh.z), a4); a5 = fmaf(e, b2f_hi(uh.z), a5);
    a6 = fmaf(e, b2f_lo(uh.w), a6); a7 = fmaf(e, b2f_hi(uh.w), a7);
    uint4 o;
    o.x = ((unsigned int)f2b(a1) << 16) | (unsigned int)f2b(a0);
    o.y = ((unsigned int)f2b(a3) << 16) | (unsigned int)f2b(a2);
    o.z = ((unsigned int)f2b(a5) << 16) | (unsigned int)f2b(a4);
    o.w = ((unsigned int)f2b(a7) << 16) | (unsigned int)f2b(a6);
    *(uint4*)(Z + ((long long)node << 7) + c8) = o;
}

// ---------------- MFMA matmul (LDS-free, packed-B fragments) ----------------
template<int KIN, int KOUT, bool RELU, bool HASBIAS, bool OUTF32>
__global__ __launch_bounds__(256) void mm_mfma(
        const unsigned short* __restrict__ Zin, const unsigned short* __restrict__ Wp,
        const float* __restrict__ bias, void* __restrict__ outv, int Mreal) {
    constexpr int KS = KIN / 32;
    constexpr int NT = KOUT / 16;
    const int tid = threadIdx.x;
    const int w = tid >> 6;
    const int l = tid & 63;
    const int lm = l & 15;
    const int lk = l >> 4;
    const long long arow = (long long)blockIdx.x * 64 + w * 16 + lm;
    const unsigned short* zrow = Zin + arow * KIN + lk * 8;

    float4v acc[NT];
#pragma unroll
    for (int t = 0; t < NT; ++t) acc[t] = (float4v){0.f, 0.f, 0.f, 0.f};

#pragma unroll
    for (int s = 0; s < KS; ++s) {
        short8 a = *(const short8*)(zrow + s * 32);
#pragma unroll
        for (int t = 0; t < NT; ++t) {
            short8 b = *(const short8*)(Wp + (long long)((t * KS + s) * 64 + l) * 8);
            acc[t] = __builtin_amdgcn_mfma_f32_16x16x32_bf16(a, b, acc[t], 0, 0, 0);
        }
    }

    const long long orow0 = (long long)blockIdx.x * 64 + w * 16 + lk * 4;
#pragma unroll
    for (int t = 0; t < NT; ++t) {
        const int n = t * 16 + lm;
        const float bv = HASBIAS ? bias[n] : 0.f;
#pragma unroll
        for (int r = 0; r < 4; ++r) {
            float v = acc[t][r] + bv;
            if (RELU) v = fmaxf(v, 0.f);
            const long long orow = orow0 + r;
            if (OUTF32) {
                if (orow < Mreal) ((float*)outv)[orow * KOUT + n] = v;
            } else {
                ((unsigned short*)outv)[orow * KOUT + n] = f2b(v);
            }
        }
    }
}

extern "C" void kernel_launch(void* const* d_in, const int* in_sizes, int n_in,
                              void* d_out, int out_size, void* d_ws, size_t ws_size,
                              hipStream_t stream) {
    const float* x    = (const float*)d_in[0];
    const int*   ei   = (const int*)d_in[1];
    const float* Wemb = (const float*)d_in[2];
    const float* eps1 = (const float*)d_in[3];
    const float* w1a  = (const float*)d_in[4];
    const float* b1a  = (const float*)d_in[5];
    const float* w1b  = (const float*)d_in[6];
    const float* b1b  = (const float*)d_in[7];
    const float* eps2 = (const float*)d_in[8];
    const float* w2a  = (const float*)d_in[9];
    const float* b2a  = (const float*)d_in[10];
    const float* w2b  = (const float*)d_in[11];
    const float* b2b  = (const float*)d_in[12];
    const float* eps3 = (const float*)d_in[13];
    const float* w3a  = (const float*)d_in[14];
    const float* b3a  = (const float*)d_in[15];
    const float* w3b  = (const float*)d_in[16];
    const float* b3b  = (const float*)d_in[17];

    const int N = in_sizes[0] / 64;   // 100000
    const int E = in_sizes[1] / 2;    // 1600000
    const int Mpad = ((N + 63) / 64) * 64;
    const int NB = (N + BKT - 1) / BKT;   // 196
    const int G2 = 256;
    const int PB = (E + G2 - 1) / G2;
    const int BH = NB * G2;

    char* ws = (char*)d_ws;
    size_t off = 0;
    auto alloc = [&](size_t bytes) -> void* {
        void* p = ws + off;
        off = (off + bytes + 255) & ~(size_t)255;
        return p;
    };
    unsigned short* xb  = (unsigned short*)alloc((size_t)Mpad * 64 * 2);
    unsigned short* Hb  = (unsigned short*)alloc((size_t)Mpad * 128 * 2);
    unsigned short* Zb  = (unsigned short*)alloc((size_t)Mpad * 128 * 2);
    unsigned short* Tb  = (unsigned short*)alloc((size_t)Mpad * 256 * 2);
    unsigned short* pWe = (unsigned short*)alloc((size_t)64 * 128 * 2);
    unsigned short* p1a = (unsigned short*)alloc((size_t)128 * 128 * 2);
    unsigned short* p1b = (unsigned short*)alloc((size_t)128 * 128 * 2);
    unsigned short* p2a = (unsigned short*)alloc((size_t)128 * 256 * 2);
    unsigned short* p2b = (unsigned short*)alloc((size_t)256 * 128 * 2);
    unsigned short* p3a = (unsigned short*)alloc((size_t)128 * 256 * 2);
    unsigned short* p3b = (unsigned short*)alloc((size_t)256 * 128 * 2);
    int* offs = (int*)alloc((size_t)(N + 1) * 4);
    int* csr  = (int*)alloc((size_t)E * 4);
    int* bh   = (int*)alloc((size_t)BH * 4);
    int* bhs  = (int*)alloc((size_t)BH * 4);
    int* part = (int*)alloc(1024);
    int* boff = (int*)alloc(1024);
    int* flag = (int*)alloc(256);

    // CSR staging aliased into Tb (first real use of Tb is the mm phase).
    unsigned int* staged = (unsigned int*)Tb;

    // ---- CSR build ----
    detect_i64_kernel<<<1, 64, 0, stream>>>((const unsigned int*)ei, flag);
    part_hist_kernel<<<G2, 256, 0, stream>>>(ei, flag, bh, E, NB, PB);
    const int G1 = (BH + 1023) / 1024;
    scan1_kernel<<<G1, 1024, 0, stream>>>(bh, bhs, part, BH);
    scan2_kernel<<<1, 128, 0, stream>>>(part, boff, G1);
    scan3g_kernel<<<G1, 1024, 0, stream>>>(bhs, boff, BH);
    part_scatter_kernel<<<G2, 256, 0, stream>>>(ei, flag, bhs, staged, E, NB, PB);
    csr_local_kernel<<<NB, 256, 0, stream>>>(staged, bhs, offs, csr, N, E, NB, G2);

    // ---- conversions / fused weight packing ----
    xconv_kernel<<<(Mpad * 64 + 255) / 256, 256, 0, stream>>>(x, xb, N * 64, Mpad * 64);
    {
        PWAll P;
        const PW descs[7] = {
            {Wemb, pWe, 64, 128}, {w1a, p1a, 128, 128}, {w1b, p1b, 128, 128},
            {w2a, p2a, 128, 256}, {w2b, p2b, 256, 128}, {w3a, p3a, 128, 256},
            {w3b, p3b, 256, 128}};
        int c = 0;
        for (int k = 0; k < 7; ++k) {
            P.d[k] = descs[k];
            P.cum[k] = c;
            c += (descs[k].KOUT / 16) * (descs[k].K / 32) * 64;
        }
        P.cum[7] = c;
        packall_kernel<<<(c + 255) / 256, 256, 0, stream>>>(P);
    }

    const int MMB = Mpad / 64;
    const int AGB = (N + 15) / 16;   // 16 nodes per block

    // ---- embed: H = x @ W_embed ----
    mm_mfma<64, 128, false, false, false><<<MMB, 256, 0, stream>>>(xb, pWe, nullptr, Hb, N);

    // ---- layer 1 ----
    aggz_kernel<<<AGB, 256, 0, stream>>>(Hb, offs, csr, eps1, Zb, N);
    mm_mfma<128, 128, true,  true, false><<<MMB, 256, 0, stream>>>(Zb, p1a, b1a, Tb, N);
    mm_mfma<128, 128, false, true, false><<<MMB, 256, 0, stream>>>(Tb, p1b, b1b, Hb, N);

    // ---- layer 2 ----
    aggz_kernel<<<AGB, 256, 0, stream>>>(Hb, offs, csr, eps2, Zb, N);
    mm_mfma<128, 256, true, true, false><<<MMB, 256, 0, stream>>>(Zb, p2a, b2a, Tb, N);
    mm_mfma<256, 128, true, true, false><<<MMB, 256, 0, stream>>>(Tb, p2b, b2b, Hb, N);

    // ---- layer 3 ----
    aggz_kernel<<<AGB, 256, 0, stream>>>(Hb, offs, csr, eps3, Zb, N);
    mm_mfma<128, 256, true, true, false><<<MMB, 256, 0, stream>>>(Zb, p3a, b3a, Tb, N);
    mm_mfma<256, 128, true, true, true><<<MMB, 256, 0, stream>>>(Tb, p3b, b3b, d_out, N);
}

// Round 8
// 510.226 us; speedup vs baseline: 3.6392x; 1.1485x over previous
//
#include <hip/hip_runtime.h>
#include <hip/hip_bf16.h>
#include <stdint.h>

// ---------------------------------------------------------------------------
// GIN forward, round 8: register-tiled 32x32x16 MFMA matmuls (64x64 per wave,
// 128x128 per block, 2x2 frag grid => 4 MFMAs per 4 loads), radix-partition
// CSR (1024-block passes), aggz row-gather (unroll x4, request-rate floor).
// ---------------------------------------------------------------------------

typedef __attribute__((ext_vector_type(8))) short short8;
typedef __attribute__((ext_vector_type(16))) float float16v;

#define BKT 512       // nodes per bucket (dst >> 9)
#define NBMAX 256     // max buckets held in LDS (NB = 196 here)

__device__ __forceinline__ float b2f_lo(unsigned int u) {
    return __uint_as_float(u << 16);
}
__device__ __forceinline__ float b2f_hi(unsigned int u) {
    return __uint_as_float(u & 0xffff0000u);
}
__device__ __forceinline__ unsigned short f2b(float f) {
    unsigned int u = __float_as_uint(f);
    return (unsigned short)((u + 0x7fffu + ((u >> 16) & 1u)) >> 16);  // RNE
}

// ---------------- edge-index dtype detection ----------------
__global__ void detect_i64_kernel(const unsigned int* ei, int* flag) {
    if (threadIdx.x == 0) {
        int is64 = 1;
        for (int e = 0; e < 64; ++e)
            if (ei[2 * e + 1] != 0u) { is64 = 0; break; }
        *flag = is64;
    }
}

__device__ __forceinline__ int edge_at(const int* ei32, int is64, long long pos) {
    if (is64) return (int)(((const long long*)ei32)[pos]);
    return ei32[pos];
}

// ---------------- radix partition pass 1: per-(block,bucket) histogram ----------------
__global__ __launch_bounds__(256) void part_hist_kernel(
        const int* __restrict__ ei, const int* __restrict__ flag,
        int* __restrict__ bh, int E, int NB, int PB) {
    __shared__ int h[NBMAX];
    const int g = blockIdx.x, tid = threadIdx.x;
    const int is64 = *flag;
    for (int i = tid; i < NB; i += 256) h[i] = 0;
    __syncthreads();
    const int e0 = g * PB, e1 = min(e0 + PB, E);
    for (int e = e0 + tid; e < e1; e += 256) {
        int d = edge_at(ei, is64, (long long)E + e);
        atomicAdd(&h[d >> 9], 1);
    }
    __syncthreads();
    for (int i = tid; i < NB; i += 256) bh[i * gridDim.x + g] = h[i];
}

// ---------------- generic multi-block exclusive scan ----------------
__global__ __launch_bounds__(1024) void scan1_kernel(
        const int* __restrict__ in, int* __restrict__ out,
        int* __restrict__ partial, int n) {
    __shared__ int sm[1024];
    const int t = threadIdx.x;
    const int i = blockIdx.x * 1024 + t;
    int v = (i < n) ? in[i] : 0;
    sm[t] = v;
    __syncthreads();
#pragma unroll
    for (int off = 1; off < 1024; off <<= 1) {
        int x = (t >= off) ? sm[t - off] : 0;
        __syncthreads();
        sm[t] += x;
        __syncthreads();
    }
    if (i < n) out[i] = sm[t] - v;
    if (t == 1023) partial[blockIdx.x] = sm[1023];
}

__global__ __launch_bounds__(256) void scan2_kernel(
        int* __restrict__ partial, int* __restrict__ blockoff, int g1) {
    __shared__ int sm[256];
    const int t = threadIdx.x;
    int v = (t < g1) ? partial[t] : 0;
    sm[t] = v;
    __syncthreads();
#pragma unroll
    for (int off = 1; off < 256; off <<= 1) {
        int x = (t >= off) ? sm[t - off] : 0;
        __syncthreads();
        sm[t] += x;
        __syncthreads();
    }
    blockoff[t] = sm[t] - v;
}

__global__ __launch_bounds__(1024) void scan3g_kernel(
        int* __restrict__ a, const int* __restrict__ blockoff, int n) {
    int i = blockIdx.x * 1024 + threadIdx.x;
    if (i < n) a[i] += blockoff[blockIdx.x];
}

// ---------------- pass 2: scatter edges into bucket-contiguous staging ----------------
// staged entry: (dlocal<<17) | src
__global__ __launch_bounds__(256) void part_scatter_kernel(
        const int* __restrict__ ei, const int* __restrict__ flag,
        const int* __restrict__ bhs, unsigned int* __restrict__ staged,
        int E, int NB, int PB) {
    __shared__ int cur[NBMAX];
    const int g = blockIdx.x, tid = threadIdx.x;
    const int is64 = *flag;
    for (int i = tid; i < NB; i += 256) cur[i] = bhs[i * gridDim.x + g];
    __syncthreads();
    const int e0 = g * PB, e1 = min(e0 + PB, E);
    for (int e = e0 + tid; e < e1; e += 256) {
        int d = edge_at(ei, is64, (long long)E + e);
        int s = edge_at(ei, is64, (long long)e);
        int b = d >> 9;
        int p = atomicAdd(&cur[b], 1);
        staged[p] = ((unsigned int)(d & (BKT - 1)) << 17) | (unsigned int)s;
    }
}

// ---------------- pass 3: per-bucket counting sort -> offs + csr ----------------
__global__ __launch_bounds__(256) void csr_local_kernel(
        const unsigned int* __restrict__ staged, const int* __restrict__ bhs,
        int* __restrict__ offs, int* __restrict__ csr, int N, int E, int NB, int G2) {
    __shared__ int hist[BKT];
    __shared__ int cur[BKT];
    const int b = blockIdx.x;
    const int tid = threadIdx.x;
    const int start = bhs[b * G2];
    const int end = (b + 1 < NB) ? bhs[(b + 1) * G2] : E;
    const int node0 = b * BKT;
    for (int i = tid; i < BKT; i += 256) hist[i] = 0;
    __syncthreads();
    for (int i = start + tid; i < end; i += 256)
        atomicAdd(&hist[staged[i] >> 17], 1);
    __syncthreads();
    const int i0 = tid * 2, i1 = i0 + 1;
    for (int off = 1; off < BKT; off <<= 1) {
        int v0 = (i0 >= off) ? hist[i0 - off] : 0;
        int v1 = (i1 >= off) ? hist[i1 - off] : 0;
        __syncthreads();
        hist[i0] += v0;
        hist[i1] += v1;
        __syncthreads();
    }
    for (int i = tid; i < BKT; i += 256) {
        int node = node0 + i;
        if (node < N) {
            int e0 = start + ((i == 0) ? 0 : hist[i - 1]);
            offs[node] = e0;
            cur[i] = e0;
        }
    }
    if (b == NB - 1 && tid == 0) offs[N] = E;
    __syncthreads();
    for (int i = start + tid; i < end; i += 256) {
        unsigned int v = staged[i];
        int dl = v >> 17;
        int src = (int)(v & 0x1ffff);
        int p = atomicAdd(&cur[dl], 1);
        csr[p] = src;
    }
}

// ---------------- conversions ----------------
__global__ void xconv_kernel(const float* __restrict__ x, unsigned short* __restrict__ xb,
                             int total_real, int total_pad) {
    int i = blockIdx.x * blockDim.x + threadIdx.x;
    if (i >= total_pad) return;
    xb[i] = (i < total_real) ? f2b(x[i]) : (unsigned short)0;
}

// Fused weight pack for 32x32x16 MFMA B-fragments, all 7 weights.
// out[((T*KS + s)*64 + l)*8 + j] = bf16(W[(s*16 + (l>>5)*8 + j)*KOUT + T*32 + (l&31)])
struct PW { const float* W; unsigned short* o; int K; int KOUT; };
struct PWAll { PW d[7]; int cum[8]; };

__global__ __launch_bounds__(256) void packall_kernel(PWAll P) {
    int id = blockIdx.x * blockDim.x + threadIdx.x;
    if (id >= P.cum[7]) return;
    int w = 0;
#pragma unroll
    for (int k = 1; k < 7; ++k) w += (id >= P.cum[k]);
    const int local = id - P.cum[w];
    const float* W = P.d[w].W;
    unsigned short* out = P.d[w].o;
    const int K = P.d[w].K, KOUT = P.d[w].KOUT;
    const int KS = K / 16;
    const int l = local & 63;
    const int s = (local >> 6) % KS;
    const int T = local / (KS * 64);
    const int kbase = s * 16 + ((l >> 5) << 3);
    const int n = T * 32 + (l & 31);
#pragma unroll
    for (int j = 0; j < 8; ++j)
        out[(long long)local * 8 + j] = f2b(W[(long long)(kbase + j) * KOUT + n]);
}

// ---------------- aggregation: Z = (1+eps)*H + sum_{j in N(i)} H[j] ----------------
// Row-major bf16 H (128 cols = 256 B rows). 16 lanes/node, 16 B/lane dwordx4;
// unroll x4 (4 KB in flight/wave) — measured at the request-service floor.
__global__ __launch_bounds__(256) void aggz_kernel(
        const unsigned short* __restrict__ H, const int* __restrict__ offs,
        const int* __restrict__ csr, const float* __restrict__ eps,
        unsigned short* __restrict__ Z, int n) {
    const int node = blockIdx.x * 16 + (threadIdx.x >> 4);
    const int c8 = (threadIdx.x & 15) << 3;   // 8-col group base
    if (node >= n) return;
    const int beg = offs[node];
    const int end = offs[node + 1];
    float a0 = 0.f, a1 = 0.f, a2 = 0.f, a3 = 0.f;
    float a4 = 0.f, a5 = 0.f, a6 = 0.f, a7 = 0.f;
    int i = beg;
    for (; i + 3 < end; i += 4) {
        const int j0 = csr[i], j1 = csr[i + 1], j2 = csr[i + 2], j3 = csr[i + 3];
        const uint4 u0 = *(const uint4*)(H + ((long long)j0 << 7) + c8);
        const uint4 u1 = *(const uint4*)(H + ((long long)j1 << 7) + c8);
        const uint4 u2 = *(const uint4*)(H + ((long long)j2 << 7) + c8);
        const uint4 u3 = *(const uint4*)(H + ((long long)j3 << 7) + c8);
        a0 += (b2f_lo(u0.x) + b2f_lo(u1.x)) + (b2f_lo(u2.x) + b2f_lo(u3.x));
        a1 += (b2f_hi(u0.x) + b2f_hi(u1.x)) + (b2f_hi(u2.x) + b2f_hi(u3.x));
        a2 += (b2f_lo(u0.y) + b2f_lo(u1.y)) + (b2f_lo(u2.y) + b2f_lo(u3.y));
        a3 += (b2f_hi(u0.y) + b2f_hi(u1.y)) + (b2f_hi(u2.y) + b2f_hi(u3.y));
        a4 += (b2f_lo(u0.z) + b2f_lo(u1.z)) + (b2f_lo(u2.z) + b2f_lo(u3.z));
        a5 += (b2f_hi(u0.z) + b2f_hi(u1.z)) + (b2f_hi(u2.z) + b2f_hi(u3.z));
        a6 += (b2f_lo(u0.w) + b2f_lo(u1.w)) + (b2f_lo(u2.w) + b2f_lo(u3.w));
        a7 += (b2f_hi(u0.w) + b2f_hi(u1.w)) + (b2f_hi(u2.w) + b2f_hi(u3.w));
    }
    for (; i < end; ++i) {
        const int j0 = csr[i];
        const uint4 u0 = *(const uint4*)(H + ((long long)j0 << 7) + c8);
        a0 += b2f_lo(u0.x); a1 += b2f_hi(u0.x);
        a2 += b2f_lo(u0.y); a3 += b2f_hi(u0.y);
        a4 += b2f_lo(u0.z); a5 += b2f_hi(u0.z);
        a6 += b2f_lo(u0.w); a7 += b2f_hi(u0.w);
    }
    const uint4 uh = *(const uint4*)(H + ((long long)node << 7) + c8);
    const float e = 1.0f + eps[0];
    a0 = fmaf(e, b2f_lo(uh.x), a0); a1 = fmaf(e, b2f_hi(uh.x), a1);
    a2 = fmaf(e, b2f_lo(uh.y), a2); a3 = fmaf(e, b2f_hi(uh.y), a3);
    a4 = fmaf(e, b2f_lo(uh.z), a4); a5 = fmaf(e, b2f_hi(uh.z), a5);
    a6 = fmaf(e, b2f_lo(uh.w), a6); a7 = fmaf(e, b2f_hi(uh.w), a7);
    uint4 o;
    o.x = ((unsigned int)f2b(a1) << 16) | (unsigned int)f2b(a0);
    o.y = ((unsigned int)f2b(a3) << 16) | (unsigned int)f2b(a2);
    o.z = ((unsigned int)f2b(a5) << 16) | (unsigned int)f2b(a4);
    o.w = ((unsigned int)f2b(a7) << 16) | (unsigned int)f2b(a6);
    *(uint4*)(Z + ((long long)node << 7) + c8) = o;
}

// ---------------- register-tiled 32x32x16 MFMA matmul ----------------
// Wave: 64 rows x 64 cols = 2x2 fragments. Block: 4 waves = 128x128 tile.
// Grid: (Mpad/128, KOUT/128). Per k-step: 2 A + 2 B loads, 4 MFMAs.
// C/D layout (m74/m101): col = lane&31, row = (reg&3)+8*(reg>>2)+4*(lane>>5).
template<int KOUT, bool RELU, bool HASBIAS, bool OUTF32>
__device__ __forceinline__ void store_tile(float16v acc, long long row0, int col,
        const float* __restrict__ bias, void* __restrict__ outv, int Mreal) {
    const float bv = HASBIAS ? bias[col] : 0.f;
#pragma unroll
    for (int r = 0; r < 16; ++r) {
        float v = acc[r] + bv;
        if (RELU) v = fmaxf(v, 0.f);
        const long long row = row0 + (r & 3) + 8 * (r >> 2);
        if (OUTF32) {
            if (row < Mreal) ((float*)outv)[row * KOUT + col] = v;
        } else {
            ((unsigned short*)outv)[row * KOUT + col] = f2b(v);
        }
    }
}

template<int KIN, int KOUT, bool RELU, bool HASBIAS, bool OUTF32>
__global__ __launch_bounds__(256) void mm_mfma(
        const unsigned short* __restrict__ Zin, const unsigned short* __restrict__ Wp,
        const float* __restrict__ bias, void* __restrict__ outv, int Mreal) {
    constexpr int KS = KIN / 16;   // k-steps
    const int tid = threadIdx.x;
    const int w = tid >> 6;
    const int l = tid & 63;
    const int lm = l & 31;         // row (A) / col (B) within 32-tile
    const int lk = l >> 5;         // k-half (0/1)
    const int wr = w & 1, wc = w >> 1;
    const long long R0 = (long long)blockIdx.x * 128 + wr * 64;
    const int C0 = blockIdx.y * 128 + wc * 64;
    const int T0 = C0 >> 5;        // global 32-col tile index

    const unsigned short* arow0 = Zin + (R0 + lm) * KIN + lk * 8;
    const unsigned short* arow1 = arow0 + 32 * KIN;
    const unsigned short* bb0 = Wp + ((long long)T0 * KS * 64 + l) * 8;
    const unsigned short* bb1 = Wp + ((long long)(T0 + 1) * KS * 64 + l) * 8;

    float16v acc00 = {}, acc01 = {}, acc10 = {}, acc11 = {};

#pragma unroll
    for (int s = 0; s < KS; ++s) {
        short8 a0 = *(const short8*)(arow0 + s * 16);
        short8 a1 = *(const short8*)(arow1 + s * 16);
        short8 b0 = *(const short8*)(bb0 + (long long)s * 64 * 8);
        short8 b1 = *(const short8*)(bb1 + (long long)s * 64 * 8);
        acc00 = __builtin_amdgcn_mfma_f32_32x32x16_bf16(a0, b0, acc00, 0, 0, 0);
        acc01 = __builtin_amdgcn_mfma_f32_32x32x16_bf16(a0, b1, acc01, 0, 0, 0);
        acc10 = __builtin_amdgcn_mfma_f32_32x32x16_bf16(a1, b0, acc10, 0, 0, 0);
        acc11 = __builtin_amdgcn_mfma_f32_32x32x16_bf16(a1, b1, acc11, 0, 0, 0);
    }

    const long long rbase = R0 + 4 * lk;
    store_tile<KOUT, RELU, HASBIAS, OUTF32>(acc00, rbase,      C0 + lm,      bias, outv, Mreal);
    store_tile<KOUT, RELU, HASBIAS, OUTF32>(acc01, rbase,      C0 + 32 + lm, bias, outv, Mreal);
    store_tile<KOUT, RELU, HASBIAS, OUTF32>(acc10, rbase + 32, C0 + lm,      bias, outv, Mreal);
    store_tile<KOUT, RELU, HASBIAS, OUTF32>(acc11, rbase + 32, C0 + 32 + lm, bias, outv, Mreal);
}

extern "C" void kernel_launch(void* const* d_in, const int* in_sizes, int n_in,
                              void* d_out, int out_size, void* d_ws, size_t ws_size,
                              hipStream_t stream) {
    const float* x    = (const float*)d_in[0];
    const int*   ei   = (const int*)d_in[1];
    const float* Wemb = (const float*)d_in[2];
    const float* eps1 = (const float*)d_in[3];
    const float* w1a  = (const float*)d_in[4];
    const float* b1a  = (const float*)d_in[5];
    const float* w1b  = (const float*)d_in[6];
    const float* b1b  = (const float*)d_in[7];
    const float* eps2 = (const float*)d_in[8];
    const float* w2a  = (const float*)d_in[9];
    const float* b2a  = (const float*)d_in[10];
    const float* w2b  = (const float*)d_in[11];
    const float* b2b  = (const float*)d_in[12];
    const float* eps3 = (const float*)d_in[13];
    const float* w3a  = (const float*)d_in[14];
    const float* b3a  = (const float*)d_in[15];
    const float* w3b  = (const float*)d_in[16];
    const float* b3b  = (const float*)d_in[17];

    const int N = in_sizes[0] / 64;   // 100000
    const int E = in_sizes[1] / 2;    // 1600000
    const int Mpad = ((N + 127) / 128) * 128;  // 100096 (multiple of 128)
    const int NB = (N + BKT - 1) / BKT;   // 196
    const int G2 = 1024;                  // partition blocks (4 blocks/CU)
    const int PB = (E + G2 - 1) / G2;
    const int BH = NB * G2;

    char* ws = (char*)d_ws;
    size_t off = 0;
    auto alloc = [&](size_t bytes) -> void* {
        void* p = ws + off;
        off = (off + bytes + 255) & ~(size_t)255;
        return p;
    };
    unsigned short* xb  = (unsigned short*)alloc((size_t)Mpad * 64 * 2);
    unsigned short* Hb  = (unsigned short*)alloc((size_t)Mpad * 128 * 2);
    unsigned short* Zb  = (unsigned short*)alloc((size_t)Mpad * 128 * 2);
    unsigned short* Tb  = (unsigned short*)alloc((size_t)Mpad * 256 * 2);
    unsigned short* pWe = (unsigned short*)alloc((size_t)64 * 128 * 2);
    unsigned short* p1a = (unsigned short*)alloc((size_t)128 * 128 * 2);
    unsigned short* p1b = (unsigned short*)alloc((size_t)128 * 128 * 2);
    unsigned short* p2a = (unsigned short*)alloc((size_t)128 * 256 * 2);
    unsigned short* p2b = (unsigned short*)alloc((size_t)256 * 128 * 2);
    unsigned short* p3a = (unsigned short*)alloc((size_t)128 * 256 * 2);
    unsigned short* p3b = (unsigned short*)alloc((size_t)256 * 128 * 2);
    int* offs = (int*)alloc((size_t)(N + 1) * 4);
    int* csr  = (int*)alloc((size_t)E * 4);
    int* bh   = (int*)alloc((size_t)BH * 4);
    int* bhs  = (int*)alloc((size_t)BH * 4);
    int* part = (int*)alloc(1024);
    int* boff = (int*)alloc(1024);
    int* flag = (int*)alloc(256);

    // CSR staging aliased into Tb (first real use of Tb is the mm phase).
    unsigned int* staged = (unsigned int*)Tb;

    // ---- CSR build ----
    detect_i64_kernel<<<1, 64, 0, stream>>>((const unsigned int*)ei, flag);
    part_hist_kernel<<<G2, 256, 0, stream>>>(ei, flag, bh, E, NB, PB);
    const int G1 = (BH + 1023) / 1024;   // 196 <= 256
    scan1_kernel<<<G1, 1024, 0, stream>>>(bh, bhs, part, BH);
    scan2_kernel<<<1, 256, 0, stream>>>(part, boff, G1);
    scan3g_kernel<<<G1, 1024, 0, stream>>>(bhs, boff, BH);
    part_scatter_kernel<<<G2, 256, 0, stream>>>(ei, flag, bhs, staged, E, NB, PB);
    csr_local_kernel<<<NB, 256, 0, stream>>>(staged, bhs, offs, csr, N, E, NB, G2);

    // ---- conversions / fused weight packing ----
    xconv_kernel<<<(Mpad * 64 + 255) / 256, 256, 0, stream>>>(x, xb, N * 64, Mpad * 64);
    {
        PWAll P;
        const PW descs[7] = {
            {Wemb, pWe, 64, 128}, {w1a, p1a, 128, 128}, {w1b, p1b, 128, 128},
            {w2a, p2a, 128, 256}, {w2b, p2b, 256, 128}, {w3a, p3a, 128, 256},
            {w3b, p3b, 256, 128}};
        int c = 0;
        for (int k = 0; k < 7; ++k) {
            P.d[k] = descs[k];
            P.cum[k] = c;
            c += (descs[k].KOUT / 32) * (descs[k].K / 16) * 64;
        }
        P.cum[7] = c;
        packall_kernel<<<(c + 255) / 256, 256, 0, stream>>>(P);
    }

    const int MMB = Mpad / 128;      // 782
    const int AGB = (N + 15) / 16;   // 16 nodes per block
    const dim3 g1(MMB, 1), g2(MMB, 2);

    // ---- embed: H = x @ W_embed ----
    mm_mfma<64, 128, false, false, false><<<g1, 256, 0, stream>>>(xb, pWe, nullptr, Hb, N);

    // ---- layer 1 ----
    aggz_kernel<<<AGB, 256, 0, stream>>>(Hb, offs, csr, eps1, Zb, N);
    mm_mfma<128, 128, true,  true, false><<<g1, 256, 0, stream>>>(Zb, p1a, b1a, Tb, N);
    mm_mfma<128, 128, false, true, false><<<g1, 256, 0, stream>>>(Tb, p1b, b1b, Hb, N);

    // ---- layer 2 ----
    aggz_kernel<<<AGB, 256, 0, stream>>>(Hb, offs, csr, eps2, Zb, N);
    mm_mfma<128, 256, true, true, false><<<g2, 256, 0, stream>>>(Zb, p2a, b2a, Tb, N);
    mm_mfma<256, 128, true, true, false><<<g1, 256, 0, stream>>>(Tb, p2b, b2b, Hb, N);

    // ---- layer 3 ----
    aggz_kernel<<<AGB, 256, 0, stream>>>(Hb, offs, csr, eps3, Zb, N);
    mm_mfma<128, 256, true, true, false><<<g2, 256, 0, stream>>>(Zb, p3a, b3a, Tb, N);
    mm_mfma<256, 128, true, true, true><<<g1, 256, 0, stream>>>(Tb, p3b, b3b, d_out, N);
}